// Round 1
// baseline (78.730 us; speedup 1.0000x reference)
//
#include <hip/hip_runtime.h>
#include <cstdint>
#include <math.h>

#define N_FRAMES 16777216          // 2^24
#define MAX_BEATS (N_FRAMES / 8)   // 2097152
#define CHUNK 4096
#define NTHREADS 256
#define PER_THREAD (CHUNK / NTHREADS)   // 16
#define NBLOCKS (N_FRAMES / CHUNK)      // 4096

// peak test straight from the reference: x[j]>0 and x[j]==max(window +-3, -inf pad)
__device__ __forceinline__ bool peak_at_global(const float* __restrict__ x, int j) {
  if (j < 0 || j >= N_FRAMES) return false;
  const float c = x[j];
  if (!(c > 0.0f)) return false;
  float m = -INFINITY;
#pragma unroll
  for (int d = -3; d <= 3; ++d) {
    if (d == 0) continue;
    const int k = j + d;
    if (k >= 0 && k < N_FRAMES) m = fmaxf(m, x[k]);
  }
  return c >= m;
}

__global__ __launch_bounds__(NTHREADS) void k_fill(float* __restrict__ out) {
  const int i = blockIdx.x * blockDim.x + threadIdx.x;
  float4* o4 = reinterpret_cast<float4*>(out);
  if (i < MAX_BEATS / 4) o4[i] = make_float4(-1.f, -1.f, -1.f, -1.f);
}

// Shared stencil: load chunk + halo, compute peak flags for local l in [-1, CHUNK)
// flg[f] = peak(local l = f-1), f in [0, CHUNK]
__device__ __forceinline__ void load_and_flag(const float* __restrict__ x, int g0,
                                              float* xs, unsigned char* flg) {
  for (int k = threadIdx.x; k < CHUNK + 8; k += NTHREADS) {
    const int gi = g0 - 4 + k;
    xs[k] = (gi >= 0 && gi < N_FRAMES) ? x[gi] : -INFINITY;
  }
  __syncthreads();
  for (int f = threadIdx.x; f < CHUNK + 1; f += NTHREADS) {
    const float c = xs[f + 3];
    float m = fmaxf(fmaxf(xs[f], xs[f + 1]), fmaxf(xs[f + 2], xs[f + 4]));
    m = fmaxf(m, fmaxf(xs[f + 5], xs[f + 6]));
    flg[f] = (c > 0.0f && c >= m) ? 1 : 0;
  }
  __syncthreads();
}

__global__ __launch_bounds__(NTHREADS) void k_count(const float* __restrict__ x,
                                                    int* __restrict__ blockCounts) {
  __shared__ float xs[CHUNK + 8];
  __shared__ unsigned char flg[CHUNK + 1];
  __shared__ int wsum[NTHREADS / 64];
  const int b = blockIdx.x;
  const int g0 = b * CHUNK;
  load_and_flag(x, g0, xs, flg);

  const int base = threadIdx.x * PER_THREAD;
  int cnt = 0;
  unsigned char prev = flg[base];
#pragma unroll
  for (int e = 0; e < PER_THREAD; ++e) {
    const unsigned char cur = flg[base + 1 + e];
    cnt += (cur && !prev) ? 1 : 0;
    prev = cur;
  }
  for (int off = 32; off > 0; off >>= 1) cnt += __shfl_down(cnt, off, 64);
  if ((threadIdx.x & 63) == 0) wsum[threadIdx.x >> 6] = cnt;
  __syncthreads();
  if (threadIdx.x == 0) {
    int s = 0;
    for (int w = 0; w < NTHREADS / 64; ++w) s += wsum[w];
    blockCounts[b] = s;
  }
}

// single-block exclusive scan over NBLOCKS counts (256 threads x 16 each)
__global__ __launch_bounds__(NTHREADS) void k_scan(const int* __restrict__ counts,
                                                   int* __restrict__ offsets) {
  __shared__ int tsum[NTHREADS];
  const int t = threadIdx.x;
  int local[PER_THREAD];
  int s = 0;
#pragma unroll
  for (int e = 0; e < PER_THREAD; ++e) {
    local[e] = counts[t * PER_THREAD + e];
    s += local[e];
  }
  tsum[t] = s;
  __syncthreads();
  for (int off = 1; off < NTHREADS; off <<= 1) {
    const int v = tsum[t];
    const int add = (t >= off) ? tsum[t - off] : 0;
    __syncthreads();
    tsum[t] = v + add;
    __syncthreads();
  }
  int excl = tsum[t] - s;  // exclusive prefix for this thread's segment
#pragma unroll
  for (int e = 0; e < PER_THREAD; ++e) {
    offsets[t * PER_THREAD + e] = excl;
    excl += local[e];
  }
}

__global__ __launch_bounds__(NTHREADS) void k_emit(const float* __restrict__ x,
                                                   const int* __restrict__ blockOffsets,
                                                   float* __restrict__ out) {
  __shared__ float xs[CHUNK + 8];
  __shared__ unsigned char flg[CHUNK + 1];
  __shared__ int tscan[NTHREADS];
  const int b = blockIdx.x;
  const int g0 = b * CHUNK;
  load_and_flag(x, g0, xs, flg);

  const int base = threadIdx.x * PER_THREAD;
  int cnt = 0;
  {
    unsigned char prev = flg[base];
#pragma unroll
    for (int e = 0; e < PER_THREAD; ++e) {
      const unsigned char cur = flg[base + 1 + e];
      cnt += (cur && !prev) ? 1 : 0;
      prev = cur;
    }
  }
  tscan[threadIdx.x] = cnt;
  __syncthreads();
  for (int off = 1; off < NTHREADS; off <<= 1) {
    const int v = tscan[threadIdx.x];
    const int add = (threadIdx.x >= off) ? tscan[threadIdx.x - off] : 0;
    __syncthreads();
    tscan[threadIdx.x] = v + add;
    __syncthreads();
  }
  int sid = blockOffsets[b] + tscan[threadIdx.x] - cnt;

  unsigned char prev = flg[base];
  for (int e = 0; e < PER_THREAD; ++e) {
    const unsigned char cur = flg[base + 1 + e];
    if (cur && !prev) {
      const int i0 = g0 + base + e;     // run start (global)
      int l = base + e;                 // local pos of run end so far
      while (l + 1 < CHUNK && flg[l + 2]) ++l;
      int endj = g0 + l;
      if (l == CHUNK - 1) {             // run may continue into next chunk (rare: ties)
        int j = g0 + CHUNK;
        while (peak_at_global(x, j)) { endj = j; ++j; }
      }
      if (sid < MAX_BEATS)
        out[sid] = (float)(((double)i0 + (double)endj) * 0.5);
      ++sid;
    }
    prev = cur;
  }
}

extern "C" void kernel_launch(void* const* d_in, const int* in_sizes, int n_in,
                              void* d_out, int out_size, void* d_ws, size_t ws_size,
                              hipStream_t stream) {
  const float* x = (const float*)d_in[0];
  float* out = (float*)d_out;
  int* counts = (int*)d_ws;
  int* offsets = counts + NBLOCKS;

  k_fill<<<MAX_BEATS / 4 / NTHREADS, NTHREADS, 0, stream>>>(out);
  k_count<<<NBLOCKS, NTHREADS, 0, stream>>>(x, counts);
  k_scan<<<1, NTHREADS, 0, stream>>>(counts, offsets);
  k_emit<<<NBLOCKS, NTHREADS, 0, stream>>>(x, offsets, out);
}

// Round 2
// 43.530 us; speedup vs baseline: 1.8086x; 1.8086x over previous
//
#include <hip/hip_runtime.h>
#include <cstdint>
#include <math.h>

#define N_FRAMES 16777216          // 2^24
#define MAX_BEATS (N_FRAMES / 8)   // 2097152
#define CHUNK 4096
#define NTHREADS 256
#define PER_THREAD (CHUNK / NTHREADS)   // 16
#define NBLOCKS (N_FRAMES / CHUNK)      // 4096
#define TOTAL_MASKS ((size_t)NBLOCKS * 64)

typedef unsigned long long u64;

// peak test straight from the reference: x[j]>0 and x[j]==max(window +-3, -inf pad)
__device__ __forceinline__ bool peak_at_global(const float* __restrict__ x, int j) {
  if (j < 0 || j >= N_FRAMES) return false;
  const float c = x[j];
  if (!(c > 0.0f)) return false;
  float m = -INFINITY;
#pragma unroll
  for (int d = -3; d <= 3; ++d) {
    if (d == 0) continue;
    const int k = j + d;
    if (k >= 0 && k < N_FRAMES) m = fmaxf(m, x[k]);
  }
  return c >= m;
}

// xs[k] = x[g0 - 8 + k], k in [0, CHUNK+16)
__device__ __forceinline__ void stage_chunk(const float* __restrict__ x, int b, float* xs) {
  const int g0 = b * CHUNK;
  if (b != 0 && b != NBLOCKS - 1) {
    float4* xs4 = reinterpret_cast<float4*>(xs);
    const float4* g4 = reinterpret_cast<const float4*>(x + g0 - 8);
    for (int k = threadIdx.x; k < (CHUNK + 16) / 4; k += blockDim.x) xs4[k] = g4[k];
  } else {
    for (int k = threadIdx.x; k < CHUNK + 16; k += blockDim.x) {
      const int gi = g0 - 8 + k;
      xs[k] = (gi >= 0 && gi < N_FRAMES) ? x[gi] : -INFINITY;
    }
  }
  __syncthreads();
}

// peak at local element l (element g0+l), valid for l in [-1, CHUNK]
__device__ __forceinline__ bool peak_ls(const float* xs, int l) {
  const float c = xs[l + 8];
  float m = fmaxf(fmaxf(xs[l + 5], xs[l + 6]),
                  fmaxf(xs[l + 7], xs[l + 9]));
  m = fmaxf(m, fmaxf(xs[l + 10], xs[l + 11]));
  return (c > 0.0f) && (c >= m);
}

__global__ __launch_bounds__(NTHREADS) void k_fill(float* __restrict__ out) {
  const int i = blockIdx.x * blockDim.x + threadIdx.x;
  float4* o4 = reinterpret_cast<float4*>(out);
  if (i < MAX_BEATS / 4) o4[i] = make_float4(-1.f, -1.f, -1.f, -1.f);
}

__global__ __launch_bounds__(NTHREADS) void k_count(const float* __restrict__ x,
                                                    int* __restrict__ blockCounts,
                                                    u64* __restrict__ masks) {
  __shared__ float xs[CHUNK + 16];
  __shared__ int wsum[NTHREADS / 64];
  const int b = blockIdx.x;
  stage_chunk(x, b, xs);

  const int w = threadIdx.x >> 6;
  const int lane = threadIdx.x & 63;
  const int wbase = w * 1024;

  u64 carry = peak_ls(xs, wbase - 1) ? 1ull : 0ull;
  int cnt = 0;
#pragma unroll 4
  for (int it = 0; it < 16; ++it) {
    const int l = wbase + it * 64 + lane;
    const bool p = peak_ls(xs, l);
    const u64 mask = __ballot(p);
    const u64 sm = mask & ~((mask << 1) | carry);
    cnt += __popcll(sm);
    if (masks && lane == 0) masks[((size_t)b << 6) + (w << 4) + it] = mask;
    carry = mask >> 63;
  }
  if (lane == 0) wsum[w] = cnt;  // cnt is wave-uniform (ballot-derived)
  __syncthreads();
  if (threadIdx.x == 0)
    blockCounts[b] = wsum[0] + wsum[1] + wsum[2] + wsum[3];
}

// single-block exclusive scan over NBLOCKS counts (256 threads x 16 each)
__global__ __launch_bounds__(NTHREADS) void k_scan(const int* __restrict__ counts,
                                                   int* __restrict__ offsets) {
  __shared__ int tsum[NTHREADS];
  const int t = threadIdx.x;
  int local[PER_THREAD];
  int s = 0;
#pragma unroll
  for (int e = 0; e < PER_THREAD; ++e) {
    local[e] = counts[t * PER_THREAD + e];
    s += local[e];
  }
  tsum[t] = s;
  __syncthreads();
  for (int off = 1; off < NTHREADS; off <<= 1) {
    const int v = tsum[t];
    const int add = (t >= off) ? tsum[t - off] : 0;
    __syncthreads();
    tsum[t] = v + add;
    __syncthreads();
  }
  int excl = tsum[t] - s;
#pragma unroll
  for (int e = 0; e < PER_THREAD; ++e) {
    offsets[t * PER_THREAD + e] = excl;
    excl += local[e];
  }
}

// mask-based emit: 64 threads/block, thread t owns mask (b*64+t) = 64 elements
__global__ __launch_bounds__(64) void k_emit_masks(const u64* __restrict__ masks,
                                                   const int* __restrict__ blockOffsets,
                                                   float* __restrict__ out) {
  const int b = blockIdx.x;
  const int t = threadIdx.x;
  const size_t mi = ((size_t)b << 6) + t;
  const u64 m = masks[mi];
  const u64 prev = (mi == 0) ? 0ull : masks[mi - 1];
  const u64 carry = prev >> 63;
  u64 sm = m & ~((m << 1) | carry);
  const int cnt = __popcll(sm);

  int incl = cnt;
#pragma unroll
  for (int off = 1; off < 64; off <<= 1) {
    const int v = __shfl_up(incl, off, 64);
    if (t >= off) incl += v;
  }
  int sid = blockOffsets[b] + incl - cnt;

  const int gbase = b * CHUNK + t * 64;
  while (sm) {
    const int s = __builtin_ctzll(sm);
    sm &= sm - 1;
    const int i0 = gbase + s;
    const u64 above = m >> s;            // bit 0 = this peak
    const int len = (~above == 0ull) ? (64 - s) : __builtin_ctzll(~above);
    int end = i0 + len - 1;
    if (s + len == 64) {                 // run may continue into next mask (ties; rare)
      size_t idx = mi + 1;
      while (idx < TOTAL_MASKS) {
        const u64 mm = masks[idx];
        if (~mm == 0ull) { end += 64; ++idx; }
        else { end += __builtin_ctzll(~mm); break; }
      }
    }
    if (sid < MAX_BEATS)
      out[sid] = (float)(((double)i0 + (double)end) * 0.5);
    ++sid;
  }
}

// fallback emit when ws too small for masks: recompute ballots from x
__global__ __launch_bounds__(NTHREADS) void k_emit_recompute(const float* __restrict__ x,
                                                             const int* __restrict__ blockOffsets,
                                                             float* __restrict__ out) {
  __shared__ float xs[CHUNK + 16];
  __shared__ u64 lm[64];
  __shared__ bool pm1s;
  const int b = blockIdx.x;
  const int g0 = b * CHUNK;
  stage_chunk(x, b, xs);

  const int w = threadIdx.x >> 6;
  const int lane = threadIdx.x & 63;
  const int wbase = w * 1024;
  if (threadIdx.x == 0) pm1s = peak_ls(xs, -1);
  for (int it = 0; it < 16; ++it) {
    const int l = wbase + it * 64 + lane;
    const u64 mask = __ballot(peak_ls(xs, l));
    if (lane == 0) lm[(w << 4) + it] = mask;
  }
  __syncthreads();

  if (threadIdx.x < 64) {
    const int t = threadIdx.x;
    const u64 m = lm[t];
    const u64 carry = (t == 0) ? (pm1s ? 1ull : 0ull) : (lm[t - 1] >> 63);
    u64 sm = m & ~((m << 1) | carry);
    const int cnt = __popcll(sm);
    int incl = cnt;
#pragma unroll
    for (int off = 1; off < 64; off <<= 1) {
      const int v = __shfl_up(incl, off, 64);
      if (t >= off) incl += v;
    }
    int sid = blockOffsets[b] + incl - cnt;
    const int gbase = g0 + t * 64;
    while (sm) {
      const int s = __builtin_ctzll(sm);
      sm &= sm - 1;
      const int i0 = gbase + s;
      const u64 above = m >> s;
      const int len = (~above == 0ull) ? (64 - s) : __builtin_ctzll(~above);
      int end = i0 + len - 1;
      if (s + len == 64) {
        bool crossed_chunk = true;
        for (int idx = t + 1; idx < 64; ++idx) {
          const u64 mm = lm[idx];
          if (~mm == 0ull) { end += 64; }
          else { end += __builtin_ctzll(~mm); crossed_chunk = false; break; }
        }
        if (crossed_chunk) {
          int j = g0 + CHUNK;
          while (peak_at_global(x, j)) { ++end; ++j; }
        }
      }
      if (sid < MAX_BEATS)
        out[sid] = (float)(((double)i0 + (double)end) * 0.5);
      ++sid;
    }
  }
}

extern "C" void kernel_launch(void* const* d_in, const int* in_sizes, int n_in,
                              void* d_out, int out_size, void* d_ws, size_t ws_size,
                              hipStream_t stream) {
  const float* x = (const float*)d_in[0];
  float* out = (float*)d_out;

  const size_t maskBytes = TOTAL_MASKS * sizeof(u64);  // 2 MiB
  const bool has_masks = ws_size >= maskBytes + 2 * NBLOCKS * sizeof(int);

  u64* masks = has_masks ? (u64*)d_ws : nullptr;
  int* counts = (int*)((char*)d_ws + (has_masks ? maskBytes : 0));
  int* offsets = counts + NBLOCKS;

  k_fill<<<MAX_BEATS / 4 / NTHREADS, NTHREADS, 0, stream>>>(out);
  k_count<<<NBLOCKS, NTHREADS, 0, stream>>>(x, counts, masks);
  k_scan<<<1, NTHREADS, 0, stream>>>(counts, offsets);
  if (has_masks)
    k_emit_masks<<<NBLOCKS, 64, 0, stream>>>(masks, offsets, out);
  else
    k_emit_recompute<<<NBLOCKS, NTHREADS, 0, stream>>>(x, offsets, out);
}